// Round 1
// baseline (119.632 us; speedup 1.0000x reference)
//
#include <hip/hip_runtime.h>

#define TPB 384

constexpr int NSEQ = 32768;
constexpr int C0   = 2048;               // output samples per block chunk (16 chunks/batch)
constexpr float SCG = 14.4269504089f;    // 10 * log2(e)

// Halos h_l = 2*h_{l+1}+3, h5=4 -> {221,109,53,25,11,4}
// Geometry: P5 = C0/32 + 8, P_{l-1} = 2*P_l + 8.
// C0=2048 padded level widths P: {1272,632,312,152,72}; parity arrays [E|O], LE=P+4:
// {1276,636,316,156,76}; L5 out contiguous stride 72; synthesis strides {136,264,520,1032}.
// bufA: L0(2552) L2(2528) L4(2432) recon4(2176) recon2(2080) -> 2552
// bufB: L1(2544) L3(2496) L5(2304) recon3(2112) recon1(2064) -> 2544
// LDS = (2552+2544+62)*4 = 20632 B -> 7 blocks by LDS; wave cap 5 blocks * 6 waves = 30 waves/CU.
// TPB=384 >= max phase task count (318) -> every phase is ONE straight-line guarded
// block (no grid-stride loop): compiler hoists all ds_reads of a phase together.

__device__ __forceinline__ float4 ldf4(const float* p) { return *reinterpret_cast<const float4*>(p); }
__device__ __forceinline__ void   stf4(float* p, const float4 v) { *reinterpret_cast<float4*>(p) = v; }

__device__ __forceinline__ float rfl(float x) {
    return __builtin_bit_cast(float, __builtin_amdgcn_readfirstlane(__builtin_bit_cast(int, x)));
}

// y * (sigmoid(10(y-b)) + sigmoid(-10(y+b))), tb = SCG*b precomputed
__device__ __forceinline__ float gated(float y, float tb) {
    float e1 = __builtin_amdgcn_exp2f(fmaf(y, -SCG, tb));
    float e2 = __builtin_amdgcn_exp2f(fmaf(y,  SCG, tb));
    return y * (__builtin_amdgcn_rcpf(1.f + e1) + __builtin_amdgcn_rcpf(1.f + e2));
}

// Analysis level, r=4 (dense LDS): task = 4 outputs for sibling channels 2c,2c+1.
// in[2i+t] = E[i+t/2] (t even) / O[i+(t-1)/2] (t odd); window base s-221 makes this
// hold at L1 too.  ch_lp = 2c+(c&1) (QMF row-parity rule).  ONE task per thread.
template<int LEin, int LEout, int P, int PAIRS, int Nlev, bool EDGE, bool LAST>
__device__ __forceinline__ void analysis4(
    const float* __restrict__ in, float* __restrict__ out,
    const float* __restrict__ lp, const float* __restrict__ hp,
    const float* __restrict__ bias, int outBase)
{
    constexpr int TPC = P / 4;
    constexpr int TOT = PAIRS * TPC;
    static_assert(TOT <= TPB, "phase must be single-generation");
    const int task = threadIdx.x;
    if (task < TOT) {
        const int c  = task / TPC;
        const int i0 = (task - c * TPC) * 4;

        const float* pe = in + c * (2 * LEin) + i0;
        const float* po = pe + LEin;
        float a[8], b[8];
        reinterpret_cast<float4*>(a)[0] = ldf4(pe);
        reinterpret_cast<float4*>(a)[1] = ldf4(pe + 4);
        reinterpret_cast<float4*>(b)[0] = ldf4(po);
        reinterpret_cast<float4*>(b)[1] = ldf4(po + 4);

        const int sw     = c & 1;
        const int ch_lp  = 2 * c + sw;
        const int ch_hp  = 2 * c + 1 - sw;
        const float tb_l = bias[ch_lp];
        const float tb_h = bias[ch_hp];

        float vl[4], vh[4];
#pragma unroll
        for (int r = 0; r < 4; ++r) {
            float yl = 0.f, yh = 0.f;
#pragma unroll
            for (int u = 0; u < 4; ++u) {
                yl = fmaf(a[r + u], lp[2 * u], yl);
                yl = fmaf(b[r + u], lp[2 * u + 1], yl);
                yh = fmaf(a[r + u], hp[2 * u], yh);
                yh = fmaf(b[r + u], hp[2 * u + 1], yh);
            }
            float wl = gated(yl, tb_l);
            float wh = gated(yh, tb_h);
            if (EDGE) {
                const bool ok = ((unsigned)(outBase + i0 + r) < (unsigned)Nlev);
                wl = ok ? wl : 0.f;
                wh = ok ? wh : 0.f;
            }
            vl[r] = wl; vh[r] = wh;
        }

        if (LAST) {
            stf4(out + ch_lp * LEout + i0, make_float4(vl[0], vl[1], vl[2], vl[3]));
            stf4(out + ch_hp * LEout + i0, make_float4(vh[0], vh[1], vh[2], vh[3]));
        } else {
            const int j0 = i0 >> 1;
            float* ol = out + ch_lp * (2 * LEout);
            float* oh = out + ch_hp * (2 * LEout);
            *reinterpret_cast<float2*>(ol + j0)         = make_float2(vl[0], vl[2]);
            *reinterpret_cast<float2*>(ol + LEout + j0) = make_float2(vl[1], vl[3]);
            *reinterpret_cast<float2*>(oh + j0)         = make_float2(vh[0], vh[2]);
            *reinterpret_cast<float2*>(oh + LEout + j0) = make_float2(vh[1], vh[3]);
        }
    }
}

// Synthesis r=8: out[g,nl] = sum_q y_lp[j0+q]*lp[kb-2q] + y_hp[j0+q]*hp[kb-2q]
// lp-channel of group g is 2g+(g&1); j0=(nl+1)>>1 local, kb=7-(nl&1). One task/thread.
template<int Sin, int Sout, int G, int Nlev, bool EDGE>
__device__ __forceinline__ void synth8(
    const float* __restrict__ in, float* __restrict__ out,
    const float* __restrict__ lp, const float* __restrict__ hp, int outBase)
{
    constexpr int TPG = Sout / 8;
    constexpr int TOT = G * TPG;
    static_assert(TOT <= TPB, "phase must be single-generation");
    const int task = threadIdx.x;
    if (task < TOT) {
        const int g   = task / TPG;
        const int nl0 = (task - g * TPG) * 8;
        const int sw  = g & 1;

        float ya[8], yb[8];
        {
            const float* p0 = in + (2 * g + sw)     * Sin + nl0 / 2;   // lp channel
            const float* p1 = in + (2 * g + 1 - sw) * Sin + nl0 / 2;   // hp channel
            reinterpret_cast<float4*>(ya)[0] = ldf4(p0);
            reinterpret_cast<float4*>(ya)[1] = ldf4(p0 + 4);
            reinterpret_cast<float4*>(yb)[0] = ldf4(p1);
            reinterpret_cast<float4*>(yb)[1] = ldf4(p1 + 4);
        }

        float o[8];
#pragma unroll
        for (int r = 0; r < 8; ++r) {
            const int jr = (r + 1) >> 1;
            const int kb = 7 - (r & 1);
            float acc = 0.f;
#pragma unroll
            for (int q = 0; q < 4; ++q) {
                acc = fmaf(ya[jr + q], lp[kb - 2 * q], acc);
                acc = fmaf(yb[jr + q], hp[kb - 2 * q], acc);
            }
            if (EDGE) {
                const bool ok = ((unsigned)(outBase + nl0 + r) < (unsigned)Nlev);
                acc = ok ? acc : 0.f;
            }
            o[r] = acc;
        }
        float* op = out + g * Sout + nl0;
        stf4(op,     make_float4(o[0], o[1], o[2], o[3]));
        stf4(op + 4, make_float4(o[4], o[5], o[6], o[7]));
    }
}

template<bool EDGE>
__device__ __forceinline__ void run_chunk(
    const float* __restrict__ xb, float* __restrict__ ob, int s,
    float* __restrict__ bufA, float* __restrict__ bufB,
    const float* __restrict__ lp, const float* __restrict__ hp,
    const float* __restrict__ bss)
{
    const int tid = threadIdx.x;

    // Stage x window, base s-221: E[j]=x[base+2j] (bufA[0..1275]), O[j]=x[base+2j+1]
    {
        const int base = s - 221;
#pragma unroll
        for (int k = 0; k < 4; ++k) {
            const int j = tid + TPB * k;
            if (j < 1276) {
                const int g0 = base + 2 * j;
                if (EDGE) {
                    bufA[j]        = ((unsigned)g0       < (unsigned)NSEQ) ? xb[g0]     : 0.f;
                    bufA[1276 + j] = ((unsigned)(g0 + 1) < (unsigned)NSEQ) ? xb[g0 + 1] : 0.f;
                } else {
                    bufA[j]        = xb[g0];
                    bufA[1276 + j] = xb[g0 + 1];
                }
            }
        }
    }
    __syncthreads();

    // ---- analysis (r=4, parity ping-pong); task counts 318,316,312,304,288 ----
    analysis4<1276, 636, 1272,  1, 16384, EDGE, false>(bufA, bufB, lp, hp, bss + 0,  (s >> 1) - 109);
    __syncthreads();
    analysis4< 636, 316,  632,  2,  8192, EDGE, false>(bufB, bufA, lp, hp, bss + 2,  (s >> 2) - 53);
    __syncthreads();
    analysis4< 316, 156,  312,  4,  4096, EDGE, false>(bufA, bufB, lp, hp, bss + 6,  (s >> 3) - 25);
    __syncthreads();
    analysis4< 156,  76,  152,  8,  2048, EDGE, false>(bufB, bufA, lp, hp, bss + 14, (s >> 4) - 11);
    __syncthreads();
    analysis4<  76,  72,   72, 16,  1024, EDGE, true >(bufA, bufB, lp, hp, bss + 30, (s >> 5) - 4);
    __syncthreads();

    // ---- synthesis; task counts 272,264,260,258 ----
    synth8<  72,  136, 16,  2048, EDGE>(bufB, bufA, lp, hp, (s >> 4) - 4);
    __syncthreads();
    synth8< 136,  264,  8,  4096, EDGE>(bufA, bufB, lp, hp, (s >> 3) - 4);
    __syncthreads();
    synth8< 264,  520,  4,  8192, EDGE>(bufB, bufA, lp, hp, (s >> 2) - 4);
    __syncthreads();
    synth8< 520, 1032,  2, 16384, EDGE>(bufA, bufB, lp, hp, (s >> 1) - 4);
    __syncthreads();

    // ---- final level (G=1) straight to global; recon1 in bufB, stride 1032, base s/2-4 ----
    if (tid < 256) {
        const int i0 = tid * 8;
        float ya[12], yb[12];
        {
            const float* p0 = bufB + i0 / 2;          // channel 0 = lp
            const float* p1 = p0 + 1032;              // channel 1 = hp
            reinterpret_cast<float4*>(ya)[0] = ldf4(p0);
            reinterpret_cast<float4*>(ya)[1] = ldf4(p0 + 4);
            reinterpret_cast<float4*>(ya)[2] = ldf4(p0 + 8);
            reinterpret_cast<float4*>(yb)[0] = ldf4(p1);
            reinterpret_cast<float4*>(yb)[1] = ldf4(p1 + 4);
            reinterpret_cast<float4*>(yb)[2] = ldf4(p1 + 8);
        }
        float o[8];
#pragma unroll
        for (int r = 0; r < 8; ++r) {
            const int jr = ((r + 1) >> 1) + 2;
            const int kb = 7 - (r & 1);
            float acc = 0.f;
#pragma unroll
            for (int q = 0; q < 4; ++q) {
                acc = fmaf(ya[jr + q], lp[kb - 2 * q], acc);
                acc = fmaf(yb[jr + q], hp[kb - 2 * q], acc);
            }
            o[r] = acc;
        }
        stf4(ob + i0,     make_float4(o[0], o[1], o[2], o[3]));
        stf4(ob + i0 + 4, make_float4(o[4], o[5], o[6], o[7]));
    }
}

__global__ __launch_bounds__(TPB, 8) void wpt_fused(
    const float* __restrict__ x,
    const float* __restrict__ K1, const float* __restrict__ K2,
    const float* __restrict__ K3, const float* __restrict__ K4,
    const float* __restrict__ K5,
    const float* __restrict__ B1, const float* __restrict__ B2,
    const float* __restrict__ B3, const float* __restrict__ B4,
    const float* __restrict__ B5,
    float* __restrict__ out)
{
    __shared__ __align__(16) float bufA[2552];
    __shared__ __align__(16) float bufB[2544];
    __shared__ float bss[62];

    const int tid   = threadIdx.x;
    const int batch = blockIdx.x >> 4;
    const int cid   = blockIdx.x & 15;
    const int s     = cid * C0;

    // Filters in SGPRs: K1 = [lp | hp]; every level's rows are one of these two.
    float lp[8], hp[8];
#pragma unroll
    for (int t = 0; t < 8; ++t) {
        lp[t] = rfl(K1[t]);
        hp[t] = rfl(K1[8 + t]);
    }

    // Biases (pre-scaled by 10*log2(e)); 62 total, one pass with TPB=384
    {
        const float* bin[5] = {B1, B2, B3, B4, B5};
        const int boff[5] = {0, 2, 6, 14, 30};
#pragma unroll
        for (int l = 0; l < 5; ++l)
            for (int i = tid; i < (2 << l); i += TPB) bss[boff[l] + i] = SCG * bin[l][i];
    }

    const float* xb = x + batch * NSEQ;
    float* ob = out + batch * NSEQ + s;

    if (cid == 0 || cid == 15)
        run_chunk<true >(xb, ob, s, bufA, bufB, lp, hp, bss);
    else
        run_chunk<false>(xb, ob, s, bufA, bufB, lp, hp, bss);
}

extern "C" void kernel_launch(void* const* d_in, const int* in_sizes, int n_in,
                              void* d_out, int out_size, void* d_ws, size_t ws_size,
                              hipStream_t stream) {
    const int nbatch = in_sizes[0] / NSEQ;
    wpt_fused<<<dim3(nbatch * (NSEQ / C0)), dim3(TPB), 0, stream>>>(
        (const float*)d_in[0],
        (const float*)d_in[1], (const float*)d_in[2],
        (const float*)d_in[3], (const float*)d_in[4],
        (const float*)d_in[5],
        (const float*)d_in[6], (const float*)d_in[7],
        (const float*)d_in[8], (const float*)d_in[9],
        (const float*)d_in[10],
        (float*)d_out);
}

// Round 2
// 116.074 us; speedup vs baseline: 1.0307x; 1.0307x over previous
//
#include <hip/hip_runtime.h>

#define TPB 512

constexpr int NSEQ = 32768;
constexpr int C0   = 2048;               // output samples per block chunk (16 chunks/batch)
constexpr int COLW = 320;                // per-wave LDS column stride (floats) for the stretch
constexpr float SCG = 14.4269504089f;    // 10 * log2(e)

// Halos h_l = 2*h_{l+1}+3, h5=4 -> {221,109,53,25,11,4}
// Geometry: P5 = C0/32 + 8, P_{l-1} = 2*P_l + 8.
// C0=2048 padded level widths P: {1272,632,312,152,72}; parity arrays [E|O], LE=P+4 halves:
// LE = {636,316,156,76}; L5 out contiguous stride 72; synthesis Sout {136,264,520,1032}.
//
// Phase plan (7 barriers instead of 10):
//   stage | L1 | L2 | L3 | {L4,L5,s5,s4 per-wave, NO barriers} | s3 | s2 | final
// After L3 the 8 channel subtrees are independent; wave w (TPB=512 -> 8 waves) owns
// L3-out channel w. All stretch data lives in wave-column w*COLW of bufA/bufB:
//   colB: L3-out [E|O] 312 -> overwritten by L5 out (4ch x 72 = 288) -> r3 (264)
//   colA: L4 out (2ch x 152 = 304) -> r4 (2ch x 136 = 272)
// Ping-pong overwrites are column-private => only the owner wave overwrites, after it
// consumed the data (intra-wave lgkmcnt ordering, no cross-wave hazard).
//
// bufA: L0 stage (2552) | L2-out plain (2528) | stretch cols (2560) | r2 plain (2080)
// bufB: L1-out plain (2544) | L3-out cols / stretch (2560) | r1 plain (2064)
// LDS = (2560+2560+62)*4 = 20728 B. Waves cap: 32/8 = 4 blocks * 8 waves = 32 waves/CU.
// Grid 2048 blocks = exactly 2 residency generations of 4/CU (no tail).

__device__ __forceinline__ float4 ldf4(const float* p) { return *reinterpret_cast<const float4*>(p); }
__device__ __forceinline__ void   stf4(float* p, const float4 v) { *reinterpret_cast<float4*>(p) = v; }

__device__ __forceinline__ float rfl(float x) {
    return __builtin_bit_cast(float, __builtin_amdgcn_readfirstlane(__builtin_bit_cast(int, x)));
}

// y * (sigmoid(10(y-b)) + sigmoid(-10(y+b))), tb = SCG*b precomputed
__device__ __forceinline__ float gated(float y, float tb) {
    float e1 = __builtin_amdgcn_exp2f(fmaf(y, -SCG, tb));
    float e2 = __builtin_amdgcn_exp2f(fmaf(y,  SCG, tb));
    return y * (__builtin_amdgcn_rcpf(1.f + e1) + __builtin_amdgcn_rcpf(1.f + e2));
}

// Block-wide analysis level, r=4. OUTSTRIDE = channel stride of output, EOOFF = E->O offset.
// (plain layout: OUTSTRIDE = 2*LEout, EOOFF = LEout; column layout: OUTSTRIDE = COLW.)
template<int LEin, int LEout, int P, int PAIRS, int Nlev, bool EDGE, int OUTSTRIDE, int EOOFF>
__device__ __forceinline__ void analysisN(
    const float* __restrict__ in, float* __restrict__ out,
    const float* __restrict__ lp, const float* __restrict__ hp,
    const float* __restrict__ bias, int outBase)
{
    constexpr int TPC = P / 4;
    constexpr int TOT = PAIRS * TPC;
    static_assert(TOT <= TPB, "phase must be single-generation");
    const int task = threadIdx.x;
    if (task < TOT) {
        const int c  = task / TPC;
        const int i0 = (task - c * TPC) * 4;

        const float* pe = in + c * (2 * LEin) + i0;
        const float* po = pe + LEin;
        float a[8], b[8];
        reinterpret_cast<float4*>(a)[0] = ldf4(pe);
        reinterpret_cast<float4*>(a)[1] = ldf4(pe + 4);
        reinterpret_cast<float4*>(b)[0] = ldf4(po);
        reinterpret_cast<float4*>(b)[1] = ldf4(po + 4);

        const int sw     = c & 1;
        const int ch_lp  = 2 * c + sw;
        const int ch_hp  = 2 * c + 1 - sw;
        const float tb_l = bias[ch_lp];
        const float tb_h = bias[ch_hp];

        float vl[4], vh[4];
#pragma unroll
        for (int r = 0; r < 4; ++r) {
            float yl = 0.f, yh = 0.f;
#pragma unroll
            for (int u = 0; u < 4; ++u) {
                yl = fmaf(a[r + u], lp[2 * u], yl);
                yl = fmaf(b[r + u], lp[2 * u + 1], yl);
                yh = fmaf(a[r + u], hp[2 * u], yh);
                yh = fmaf(b[r + u], hp[2 * u + 1], yh);
            }
            float wl = gated(yl, tb_l);
            float wh = gated(yh, tb_h);
            if (EDGE) {
                const bool ok = ((unsigned)(outBase + i0 + r) < (unsigned)Nlev);
                wl = ok ? wl : 0.f;
                wh = ok ? wh : 0.f;
            }
            vl[r] = wl; vh[r] = wh;
        }

        const int j0 = i0 >> 1;
        float* ol = out + ch_lp * OUTSTRIDE;
        float* oh = out + ch_hp * OUTSTRIDE;
        *reinterpret_cast<float2*>(ol + j0)         = make_float2(vl[0], vl[2]);
        *reinterpret_cast<float2*>(ol + EOOFF + j0) = make_float2(vl[1], vl[3]);
        *reinterpret_cast<float2*>(oh + j0)         = make_float2(vh[0], vh[2]);
        *reinterpret_cast<float2*>(oh + EOOFF + j0) = make_float2(vh[1], vh[3]);
    }
}

// Block-wide synthesis r=8. INSTRIDE = input channel stride (col layout uses COLW).
template<int INSTRIDE, int Sout, int G, int Nlev, bool EDGE>
__device__ __forceinline__ void synthN(
    const float* __restrict__ in, float* __restrict__ out,
    const float* __restrict__ lp, const float* __restrict__ hp, int outBase)
{
    constexpr int TPG = Sout / 8;
    constexpr int TOT = G * TPG;
    static_assert(TOT <= TPB, "phase must be single-generation");
    const int task = threadIdx.x;
    if (task < TOT) {
        const int g   = task / TPG;
        const int nl0 = (task - g * TPG) * 8;
        const int sw  = g & 1;

        float ya[8], yb[8];
        {
            const float* p0 = in + (2 * g + sw)     * INSTRIDE + nl0 / 2;   // lp channel
            const float* p1 = in + (2 * g + 1 - sw) * INSTRIDE + nl0 / 2;   // hp channel
            reinterpret_cast<float4*>(ya)[0] = ldf4(p0);
            reinterpret_cast<float4*>(ya)[1] = ldf4(p0 + 4);
            reinterpret_cast<float4*>(yb)[0] = ldf4(p1);
            reinterpret_cast<float4*>(yb)[1] = ldf4(p1 + 4);
        }

        float o[8];
#pragma unroll
        for (int r = 0; r < 8; ++r) {
            const int jr = (r + 1) >> 1;
            const int kb = 7 - (r & 1);
            float acc = 0.f;
#pragma unroll
            for (int q = 0; q < 4; ++q) {
                acc = fmaf(ya[jr + q], lp[kb - 2 * q], acc);
                acc = fmaf(yb[jr + q], hp[kb - 2 * q], acc);
            }
            if (EDGE) {
                const bool ok = ((unsigned)(outBase + nl0 + r) < (unsigned)Nlev);
                acc = ok ? acc : 0.f;
            }
            o[r] = acc;
        }
        float* op = out + g * Sout + nl0;
        stf4(op,     make_float4(o[0], o[1], o[2], o[3]));
        stf4(op + 4, make_float4(o[4], o[5], o[6], o[7]));
    }
}

// Per-wave barrier-free stretch: L4, L5, s5, s4 inside wave-column w.
template<bool EDGE>
__device__ __forceinline__ void stretch_wave(
    float* __restrict__ bufA, float* __restrict__ bufB,
    const float* __restrict__ lp, const float* __restrict__ hp,
    const float* __restrict__ bss, int s)
{
    const int w    = threadIdx.x >> 6;       // subtree = L3-out channel
    const int lane = threadIdx.x & 63;
    float* colA = bufA + w * COLW;
    float* colB = bufB + w * COLW;
    const int sww = w & 1;

    // ---- L4 analysis: input ch w (colB: E@0,O@156) -> colA local {sww,1-sww}, stride 152, EO 76
    if (lane < 38) {                          // TPC = 152/4
        const int i0 = lane * 4;
        const float* pe = colB + i0;
        const float* po = pe + 156;
        float a[8], b[8];
        reinterpret_cast<float4*>(a)[0] = ldf4(pe);
        reinterpret_cast<float4*>(a)[1] = ldf4(pe + 4);
        reinterpret_cast<float4*>(b)[0] = ldf4(po);
        reinterpret_cast<float4*>(b)[1] = ldf4(po + 4);
        const float tb_l = bss[14 + 2 * w + sww];
        const float tb_h = bss[14 + 2 * w + 1 - sww];
        float vl[4], vh[4];
#pragma unroll
        for (int r = 0; r < 4; ++r) {
            float yl = 0.f, yh = 0.f;
#pragma unroll
            for (int u = 0; u < 4; ++u) {
                yl = fmaf(a[r + u], lp[2 * u], yl);
                yl = fmaf(b[r + u], lp[2 * u + 1], yl);
                yh = fmaf(a[r + u], hp[2 * u], yh);
                yh = fmaf(b[r + u], hp[2 * u + 1], yh);
            }
            float wl = gated(yl, tb_l);
            float wh = gated(yh, tb_h);
            if (EDGE) {
                const bool ok = ((unsigned)(((s >> 4) - 11) + i0 + r) < 2048u);
                wl = ok ? wl : 0.f;
                wh = ok ? wh : 0.f;
            }
            vl[r] = wl; vh[r] = wh;
        }
        const int j0 = i0 >> 1;
        float* ol = colA + sww * 152;
        float* oh = colA + (1 - sww) * 152;
        *reinterpret_cast<float2*>(ol + j0)      = make_float2(vl[0], vl[2]);
        *reinterpret_cast<float2*>(ol + 76 + j0) = make_float2(vl[1], vl[3]);
        *reinterpret_cast<float2*>(oh + j0)      = make_float2(vh[0], vh[2]);
        *reinterpret_cast<float2*>(oh + 76 + j0) = make_float2(vh[1], vh[3]);
    }

    // ---- L5 analysis (LAST): inputs local l (global c=2w+l), out colB contiguous stride 72
    // global out ch = 4w + {3l (lp), l+1 (hp)} since sw = c&1 = l.
    if (lane < 36) {                          // 2 ch * TPC(72/4=18)
        const int l  = (lane >= 18) ? 1 : 0;
        const int i0 = (lane - 18 * l) * 4;
        const float* pe = colA + l * 152 + i0;
        const float* po = pe + 76;
        float a[8], b[8];
        reinterpret_cast<float4*>(a)[0] = ldf4(pe);
        reinterpret_cast<float4*>(a)[1] = ldf4(pe + 4);
        reinterpret_cast<float4*>(b)[0] = ldf4(po);
        reinterpret_cast<float4*>(b)[1] = ldf4(po + 4);
        const int cg = 2 * w + l;
        const float tb_l = bss[30 + 2 * cg + l];
        const float tb_h = bss[30 + 2 * cg + 1 - l];
        float vl[4], vh[4];
#pragma unroll
        for (int r = 0; r < 4; ++r) {
            float yl = 0.f, yh = 0.f;
#pragma unroll
            for (int u = 0; u < 4; ++u) {
                yl = fmaf(a[r + u], lp[2 * u], yl);
                yl = fmaf(b[r + u], lp[2 * u + 1], yl);
                yh = fmaf(a[r + u], hp[2 * u], yh);
                yh = fmaf(b[r + u], hp[2 * u + 1], yh);
            }
            float wl = gated(yl, tb_l);
            float wh = gated(yh, tb_h);
            if (EDGE) {
                const bool ok = ((unsigned)(((s >> 5) - 4) + i0 + r) < 1024u);
                wl = ok ? wl : 0.f;
                wh = ok ? wh : 0.f;
            }
            vl[r] = wl; vh[r] = wh;
        }
        stf4(colB + (3 * l) * 72 + i0, make_float4(vl[0], vl[1], vl[2], vl[3]));
        stf4(colB + (l + 1) * 72 + i0, make_float4(vh[0], vh[1], vh[2], vh[3]));
    }

    // ---- s5: groups g = 2w+gl; L5 lp local = 3gl, hp local = gl+1; out r4 colA local gl*136
    if (lane < 34) {                          // 2 groups * TPG(136/8=17)
        const int gl  = (lane >= 17) ? 1 : 0;
        const int nl0 = (lane - 17 * gl) * 8;
        const float* p0 = colB + (3 * gl) * 72 + nl0 / 2;
        const float* p1 = colB + (gl + 1) * 72 + nl0 / 2;
        float ya[8], yb[8];
        reinterpret_cast<float4*>(ya)[0] = ldf4(p0);
        reinterpret_cast<float4*>(ya)[1] = ldf4(p0 + 4);
        reinterpret_cast<float4*>(yb)[0] = ldf4(p1);
        reinterpret_cast<float4*>(yb)[1] = ldf4(p1 + 4);
        float o[8];
#pragma unroll
        for (int r = 0; r < 8; ++r) {
            const int jr = (r + 1) >> 1;
            const int kb = 7 - (r & 1);
            float acc = 0.f;
#pragma unroll
            for (int q = 0; q < 4; ++q) {
                acc = fmaf(ya[jr + q], lp[kb - 2 * q], acc);
                acc = fmaf(yb[jr + q], hp[kb - 2 * q], acc);
            }
            if (EDGE) {
                const bool ok = ((unsigned)(((s >> 4) - 4) + nl0 + r) < 2048u);
                acc = ok ? acc : 0.f;
            }
            o[r] = acc;
        }
        float* op = colA + gl * 136 + nl0;
        stf4(op,     make_float4(o[0], o[1], o[2], o[3]));
        stf4(op + 4, make_float4(o[4], o[5], o[6], o[7]));
    }

    // ---- s4: group g = w; r4 lp local = sww; out r3 colB (264 floats @ col base)
    if (lane < 33) {                          // TPG = 264/8
        const int nl0 = lane * 8;
        const float* p0 = colA + sww * 136 + nl0 / 2;
        const float* p1 = colA + (1 - sww) * 136 + nl0 / 2;
        float ya[8], yb[8];
        reinterpret_cast<float4*>(ya)[0] = ldf4(p0);
        reinterpret_cast<float4*>(ya)[1] = ldf4(p0 + 4);
        reinterpret_cast<float4*>(yb)[0] = ldf4(p1);
        reinterpret_cast<float4*>(yb)[1] = ldf4(p1 + 4);
        float o[8];
#pragma unroll
        for (int r = 0; r < 8; ++r) {
            const int jr = (r + 1) >> 1;
            const int kb = 7 - (r & 1);
            float acc = 0.f;
#pragma unroll
            for (int q = 0; q < 4; ++q) {
                acc = fmaf(ya[jr + q], lp[kb - 2 * q], acc);
                acc = fmaf(yb[jr + q], hp[kb - 2 * q], acc);
            }
            if (EDGE) {
                const bool ok = ((unsigned)(((s >> 3) - 4) + nl0 + r) < 4096u);
                acc = ok ? acc : 0.f;
            }
            o[r] = acc;
        }
        stf4(colB + nl0,     make_float4(o[0], o[1], o[2], o[3]));
        stf4(colB + nl0 + 4, make_float4(o[4], o[5], o[6], o[7]));
    }
}

template<bool EDGE>
__device__ __forceinline__ void run_chunk(
    const float* __restrict__ xb, float* __restrict__ ob, int s,
    float* __restrict__ bufA, float* __restrict__ bufB,
    const float* __restrict__ lp, const float* __restrict__ hp,
    const float* __restrict__ bss)
{
    const int tid = threadIdx.x;

    // Stage x window, base s-221: E[j]=x[base+2j] (bufA[0..1275]), O[j]=x[base+2j+1]
    {
        const int base = s - 221;
#pragma unroll
        for (int k = 0; k < 3; ++k) {
            const int j = tid + TPB * k;
            if (j < 1276) {
                const int g0 = base + 2 * j;
                if (EDGE) {
                    bufA[j]        = ((unsigned)g0       < (unsigned)NSEQ) ? xb[g0]     : 0.f;
                    bufA[1276 + j] = ((unsigned)(g0 + 1) < (unsigned)NSEQ) ? xb[g0 + 1] : 0.f;
                } else {
                    bufA[j]        = xb[g0];
                    bufA[1276 + j] = xb[g0 + 1];
                }
            }
        }
    }
    __syncthreads();

    // ---- block-wide analysis L1..L3 (L3 writes wave columns) ----
    analysisN<1276, 636, 1272, 1, 16384, EDGE, 1272, 636>(bufA, bufB, lp, hp, bss + 0, (s >> 1) - 109);
    __syncthreads();
    analysisN< 636, 316,  632, 2,  8192, EDGE,  632, 316>(bufB, bufA, lp, hp, bss + 2, (s >> 2) - 53);
    __syncthreads();
    analysisN< 316, 156,  312, 4,  4096, EDGE, COLW, 156>(bufA, bufB, lp, hp, bss + 6, (s >> 3) - 25);
    __syncthreads();

    // ---- barrier-free per-wave subtree: L4, L5, s5, s4 ----
    stretch_wave<EDGE>(bufA, bufB, lp, hp, bss, s);
    __syncthreads();

    // ---- block-wide synthesis s3, s2 ----
    synthN<COLW,  520, 4,  8192, EDGE>(bufB, bufA, lp, hp, (s >> 2) - 4);   // r3 cols -> r2 plain
    __syncthreads();
    synthN< 520, 1032, 2, 16384, EDGE>(bufA, bufB, lp, hp, (s >> 1) - 4);   // r2 -> r1 plain
    __syncthreads();

    // ---- final level (G=1) straight to global; r1 in bufB stride 1032; 512 x 4 outputs ----
    {
        const int i0 = tid * 4;
        const float* p0 = bufB + i0 / 2;          // channel 0 = lp
        const float* p1 = p0 + 1032;              // channel 1 = hp
        float ya[8], yb[8];
        reinterpret_cast<float4*>(ya)[0] = ldf4(p0);
        reinterpret_cast<float4*>(ya)[1] = ldf4(p0 + 4);
        reinterpret_cast<float4*>(yb)[0] = ldf4(p1);
        reinterpret_cast<float4*>(yb)[1] = ldf4(p1 + 4);
        float o[4];
#pragma unroll
        for (int r = 0; r < 4; ++r) {
            const int jr = ((r + 1) >> 1) + 2;
            const int kb = 7 - (r & 1);
            float acc = 0.f;
#pragma unroll
            for (int q = 0; q < 4; ++q) {
                acc = fmaf(ya[jr + q], lp[kb - 2 * q], acc);
                acc = fmaf(yb[jr + q], hp[kb - 2 * q], acc);
            }
            o[r] = acc;
        }
        stf4(ob + i0, make_float4(o[0], o[1], o[2], o[3]));
    }
}

__global__ __launch_bounds__(TPB, 8) void wpt_fused(
    const float* __restrict__ x,
    const float* __restrict__ K1, const float* __restrict__ K2,
    const float* __restrict__ K3, const float* __restrict__ K4,
    const float* __restrict__ K5,
    const float* __restrict__ B1, const float* __restrict__ B2,
    const float* __restrict__ B3, const float* __restrict__ B4,
    const float* __restrict__ B5,
    float* __restrict__ out)
{
    __shared__ __align__(16) float bufA[2560];
    __shared__ __align__(16) float bufB[2560];
    __shared__ float bss[62];

    const int tid   = threadIdx.x;
    const int batch = blockIdx.x >> 4;
    const int cid   = blockIdx.x & 15;
    const int s     = cid * C0;

    // Filters in SGPRs: K1 = [lp | hp]; every level's rows are one of these two.
    float lp[8], hp[8];
#pragma unroll
    for (int t = 0; t < 8; ++t) {
        lp[t] = rfl(K1[t]);
        hp[t] = rfl(K1[8 + t]);
    }

    // Biases (pre-scaled by 10*log2(e)); 62 total, single pass with TPB=512
    {
        const float* bin[5] = {B1, B2, B3, B4, B5};
        const int boff[5] = {0, 2, 6, 14, 30};
#pragma unroll
        for (int l = 0; l < 5; ++l)
            for (int i = tid; i < (2 << l); i += TPB) bss[boff[l] + i] = SCG * bin[l][i];
    }

    const float* xb = x + batch * NSEQ;
    float* ob = out + batch * NSEQ + s;

    if (cid == 0 || cid == 15)
        run_chunk<true >(xb, ob, s, bufA, bufB, lp, hp, bss);
    else
        run_chunk<false>(xb, ob, s, bufA, bufB, lp, hp, bss);
}

extern "C" void kernel_launch(void* const* d_in, const int* in_sizes, int n_in,
                              void* d_out, int out_size, void* d_ws, size_t ws_size,
                              hipStream_t stream) {
    const int nbatch = in_sizes[0] / NSEQ;
    wpt_fused<<<dim3(nbatch * (NSEQ / C0)), dim3(TPB), 0, stream>>>(
        (const float*)d_in[0],
        (const float*)d_in[1], (const float*)d_in[2],
        (const float*)d_in[3], (const float*)d_in[4],
        (const float*)d_in[5],
        (const float*)d_in[6], (const float*)d_in[7],
        (const float*)d_in[8], (const float*)d_in[9],
        (const float*)d_in[10],
        (float*)d_out);
}

// Round 3
// 114.609 us; speedup vs baseline: 1.0438x; 1.0128x over previous
//
#include <hip/hip_runtime.h>

#define TPB 512

constexpr int NSEQ = 32768;
constexpr int C0   = 2048;               // output samples per block chunk (16 chunks/batch)
constexpr int COLW = 320;                // per-wave LDS column stride (floats) for the stretch
constexpr float SCG = 14.4269504089f;    // 10 * log2(e)

// Halos h_l = 2*h_{l+1}+3, h5=4 -> {221,109,53,25,11,4}
// Geometry: P5 = C0/32 + 8, P_{l-1} = 2*P_l + 8.
// C0=2048 padded level widths P: {1272,632,312,152,72}; parity arrays [E|O], LE halves:
// {636,316,156,76}; L5 out contiguous stride 72; synthesis Sout {136,264,520,1032}.
//
// Phase plan (7 barriers): stage | L1 | L2 | L3 | {L4,L5,s5,s4 per-wave} | s3 | s2 | final
// After L3 the 8 channel subtrees are independent; wave w owns L3-out channel w in
// LDS column w*COLW (colB: L3-out 312 -> L5 out 288 -> r3 264; colA: L4 out 304 -> r4 272).
//
// This revision: v_pk_fma_f32 packed math everywhere (analysis packs (yl,yh) with
// broadcast multiplicand; synthesis packs (o[2k+1],o[2k+2])); analysis r=8 (float4
// LDS writes, read-amp 1.5); final phase back to 256x8 (16B-aligned reads).
// LDS = (2560+2560+62)*4 = 20728 B. 4 blocks * 8 waves = 32 waves/CU cap.

typedef float f2 __attribute__((ext_vector_type(2)));

__device__ __forceinline__ f2 sp(float x) { return (f2){x, x}; }
__device__ __forceinline__ f2 fma2(f2 a, f2 b, f2 c) { return __builtin_elementwise_fma(a, b, c); }

__device__ __forceinline__ float4 ldf4(const float* p) { return *reinterpret_cast<const float4*>(p); }
__device__ __forceinline__ void   stf4(float* p, const float4 v) { *reinterpret_cast<float4*>(p) = v; }

__device__ __forceinline__ float rfl(float x) {
    return __builtin_bit_cast(float, __builtin_amdgcn_readfirstlane(__builtin_bit_cast(int, x)));
}

// Packed gate: y * (sigmoid(10(y-b)) + sigmoid(-10(y+b))) on both halves; tb = SCG*b.
__device__ __forceinline__ f2 gated2(f2 y, f2 tb) {
    f2 t1 = fma2(y, sp(-SCG), tb);
    f2 t2 = fma2(y, sp( SCG), tb);
    f2 s;
    s[0] = __builtin_amdgcn_rcpf(1.f + __builtin_amdgcn_exp2f(t1[0]))
         + __builtin_amdgcn_rcpf(1.f + __builtin_amdgcn_exp2f(t2[0]));
    s[1] = __builtin_amdgcn_rcpf(1.f + __builtin_amdgcn_exp2f(t1[1]))
         + __builtin_amdgcn_rcpf(1.f + __builtin_amdgcn_exp2f(t2[1]));
    return y * s;
}

// Block-wide analysis, r=8 per task, packed (yl,yh).
// klh[t] = (lp[t], hp[t]).  ch_lp = 2c+(c&1).  Even/odd output passes bound liveness.
template<int LEin, int P, int PAIRS, int Nlev, bool EDGE, int OUTSTRIDE, int EOOFF>
__device__ __forceinline__ void analysis8(
    const float* __restrict__ in, float* __restrict__ out,
    const f2* __restrict__ klh, const float* __restrict__ bias, int outBase)
{
    constexpr int TPC = P / 8;
    constexpr int TOT = PAIRS * TPC;
    static_assert(TOT <= TPB, "phase must be single-generation");
    const int task = threadIdx.x;
    if (task < TOT) {
        const int c  = task / TPC;
        const int i0 = (task - c * TPC) * 8;

        const float* pe = in + c * (2 * LEin) + i0;
        const float* po = pe + LEin;
        float a[12], b[12];
        reinterpret_cast<float4*>(a)[0] = ldf4(pe);
        reinterpret_cast<float4*>(a)[1] = ldf4(pe + 4);
        reinterpret_cast<float4*>(a)[2] = ldf4(pe + 8);
        reinterpret_cast<float4*>(b)[0] = ldf4(po);
        reinterpret_cast<float4*>(b)[1] = ldf4(po + 4);
        reinterpret_cast<float4*>(b)[2] = ldf4(po + 8);

        const int sw    = c & 1;
        const int ch_lp = 2 * c + sw;
        const int ch_hp = 2 * c + 1 - sw;
        const f2  tb    = (f2){bias[ch_lp], bias[ch_hp]};

        const int j0 = i0 >> 1;
        float* ol = out + ch_lp * OUTSTRIDE;
        float* oh = out + ch_hp * OUTSTRIDE;

#pragma unroll
        for (int par = 0; par < 2; ++par) {          // par=0 -> E plane, par=1 -> O plane
            f2 w[4];
#pragma unroll
            for (int k = 0; k < 4; ++k) {
                const int r = 2 * k + par;
                f2 y = (f2){0.f, 0.f};
#pragma unroll
                for (int u = 0; u < 4; ++u) {
                    y = fma2(sp(a[r + u]), klh[2 * u], y);
                    y = fma2(sp(b[r + u]), klh[2 * u + 1], y);
                }
                y = gated2(y, tb);
                if (EDGE) {
                    const bool ok = ((unsigned)(outBase + i0 + r) < (unsigned)Nlev);
                    y[0] = ok ? y[0] : 0.f;
                    y[1] = ok ? y[1] : 0.f;
                }
                w[k] = y;
            }
            stf4(ol + par * EOOFF + j0, make_float4(w[0][0], w[1][0], w[2][0], w[3][0]));
            stf4(oh + par * EOOFF + j0, make_float4(w[0][1], w[1][1], w[2][1], w[3][1]));
        }
    }
}

// Packed synthesis core: 8 outputs from ya/yb windows.
// o[0], o[7] scalar; pairs (o1,o2),(o3,o4),(o5,o6) packed with broadcast ya/yb.
// lrev[q] = (lp[6-2q], lp[7-2q]); hrev[q] = (hp[6-2q], hp[7-2q]).  JROFF: window offset.
template<int JROFF, bool EDGE>
__device__ __forceinline__ void synth_core(
    const float* __restrict__ ya, const float* __restrict__ yb,
    const f2* __restrict__ lrev, const f2* __restrict__ hrev,
    int gpos, int Nlev, float* __restrict__ o)
{
    f2 p1 = (f2){0.f, 0.f}, p2 = (f2){0.f, 0.f}, p3 = (f2){0.f, 0.f};
    float o0 = 0.f, o7 = 0.f;
#pragma unroll
    for (int q = 0; q < 4; ++q) {
        const f2 cl = lrev[q], ch = hrev[q];
        o0 = fmaf(ya[JROFF + q],     cl[1], o0);
        o0 = fmaf(yb[JROFF + q],     ch[1], o0);
        o7 = fmaf(ya[JROFF + 4 + q], cl[0], o7);
        o7 = fmaf(yb[JROFF + 4 + q], ch[0], o7);
        p1 = fma2(sp(ya[JROFF + 1 + q]), cl, p1);
        p1 = fma2(sp(yb[JROFF + 1 + q]), ch, p1);
        p2 = fma2(sp(ya[JROFF + 2 + q]), cl, p2);
        p2 = fma2(sp(yb[JROFF + 2 + q]), ch, p2);
        p3 = fma2(sp(ya[JROFF + 3 + q]), cl, p3);
        p3 = fma2(sp(yb[JROFF + 3 + q]), ch, p3);
    }
    o[0] = o0;    o[1] = p1[0]; o[2] = p1[1]; o[3] = p2[0];
    o[4] = p2[1]; o[5] = p3[0]; o[6] = p3[1]; o[7] = o7;
    if (EDGE) {
#pragma unroll
        for (int r = 0; r < 8; ++r) {
            const bool ok = ((unsigned)(gpos + r) < (unsigned)Nlev);
            o[r] = ok ? o[r] : 0.f;
        }
    }
}

// Block-wide synthesis r=8. INSTRIDE = input channel stride (col layout uses COLW).
template<int INSTRIDE, int Sout, int G, int Nlev, bool EDGE>
__device__ __forceinline__ void synthN(
    const float* __restrict__ in, float* __restrict__ out,
    const f2* __restrict__ lrev, const f2* __restrict__ hrev, int outBase)
{
    constexpr int TPG = Sout / 8;
    constexpr int TOT = G * TPG;
    static_assert(TOT <= TPB, "phase must be single-generation");
    const int task = threadIdx.x;
    if (task < TOT) {
        const int g   = task / TPG;
        const int nl0 = (task - g * TPG) * 8;
        const int sw  = g & 1;

        float ya[8], yb[8];
        {
            const float* p0 = in + (2 * g + sw)     * INSTRIDE + nl0 / 2;   // lp channel
            const float* p1 = in + (2 * g + 1 - sw) * INSTRIDE + nl0 / 2;   // hp channel
            reinterpret_cast<float4*>(ya)[0] = ldf4(p0);
            reinterpret_cast<float4*>(ya)[1] = ldf4(p0 + 4);
            reinterpret_cast<float4*>(yb)[0] = ldf4(p1);
            reinterpret_cast<float4*>(yb)[1] = ldf4(p1 + 4);
        }
        float o[8];
        synth_core<0, EDGE>(ya, yb, lrev, hrev, outBase + nl0, Nlev, o);
        float* op = out + g * Sout + nl0;
        stf4(op,     make_float4(o[0], o[1], o[2], o[3]));
        stf4(op + 4, make_float4(o[4], o[5], o[6], o[7]));
    }
}

// Per-wave barrier-free stretch: L4, L5, s5, s4 inside wave-column w.
template<bool EDGE>
__device__ __forceinline__ void stretch_wave(
    float* __restrict__ bufA, float* __restrict__ bufB,
    const f2* __restrict__ klh, const f2* __restrict__ lrev, const f2* __restrict__ hrev,
    const float* __restrict__ bss, int s)
{
    const int w    = threadIdx.x >> 6;       // subtree = L3-out channel
    const int lane = threadIdx.x & 63;
    float* colA = bufA + w * COLW;
    float* colB = bufB + w * COLW;
    const int sww = w & 1;

    // ---- L4 analysis: colB (E@0,O@156) -> colA local {sww,1-sww}, stride 152, EO 76
    if (lane < 38) {                          // TPC = 152/4
        const int i0 = lane * 4;
        const float* pe = colB + i0;
        const float* po = pe + 156;
        float a[8], b[8];
        reinterpret_cast<float4*>(a)[0] = ldf4(pe);
        reinterpret_cast<float4*>(a)[1] = ldf4(pe + 4);
        reinterpret_cast<float4*>(b)[0] = ldf4(po);
        reinterpret_cast<float4*>(b)[1] = ldf4(po + 4);
        const f2 tb = (f2){bss[14 + 2 * w + sww], bss[14 + 2 * w + 1 - sww]};
        f2 v[4];
#pragma unroll
        for (int r = 0; r < 4; ++r) {
            f2 y = (f2){0.f, 0.f};
#pragma unroll
            for (int u = 0; u < 4; ++u) {
                y = fma2(sp(a[r + u]), klh[2 * u], y);
                y = fma2(sp(b[r + u]), klh[2 * u + 1], y);
            }
            y = gated2(y, tb);
            if (EDGE) {
                const bool ok = ((unsigned)(((s >> 4) - 11) + i0 + r) < 2048u);
                y[0] = ok ? y[0] : 0.f;
                y[1] = ok ? y[1] : 0.f;
            }
            v[r] = y;
        }
        const int j0 = i0 >> 1;
        float* ol = colA + sww * 152;
        float* oh = colA + (1 - sww) * 152;
        *reinterpret_cast<float2*>(ol + j0)      = make_float2(v[0][0], v[2][0]);
        *reinterpret_cast<float2*>(ol + 76 + j0) = make_float2(v[1][0], v[3][0]);
        *reinterpret_cast<float2*>(oh + j0)      = make_float2(v[0][1], v[2][1]);
        *reinterpret_cast<float2*>(oh + 76 + j0) = make_float2(v[1][1], v[3][1]);
    }

    // ---- L5 analysis (LAST): local l (global c=2w+l) -> colB contiguous stride 72
    // global out ch = 4w + {3l (lp), l+1 (hp)} since sw = c&1 = l.
    if (lane < 36) {                          // 2 ch * TPC(72/4=18)
        const int l  = (lane >= 18) ? 1 : 0;
        const int i0 = (lane - 18 * l) * 4;
        const float* pe = colA + l * 152 + i0;
        const float* po = pe + 76;
        float a[8], b[8];
        reinterpret_cast<float4*>(a)[0] = ldf4(pe);
        reinterpret_cast<float4*>(a)[1] = ldf4(pe + 4);
        reinterpret_cast<float4*>(b)[0] = ldf4(po);
        reinterpret_cast<float4*>(b)[1] = ldf4(po + 4);
        const int cg = 2 * w + l;
        const f2 tb = (f2){bss[30 + 2 * cg + l], bss[30 + 2 * cg + 1 - l]};
        f2 v[4];
#pragma unroll
        for (int r = 0; r < 4; ++r) {
            f2 y = (f2){0.f, 0.f};
#pragma unroll
            for (int u = 0; u < 4; ++u) {
                y = fma2(sp(a[r + u]), klh[2 * u], y);
                y = fma2(sp(b[r + u]), klh[2 * u + 1], y);
            }
            y = gated2(y, tb);
            if (EDGE) {
                const bool ok = ((unsigned)(((s >> 5) - 4) + i0 + r) < 1024u);
                y[0] = ok ? y[0] : 0.f;
                y[1] = ok ? y[1] : 0.f;
            }
            v[r] = y;
        }
        stf4(colB + (3 * l) * 72 + i0, make_float4(v[0][0], v[1][0], v[2][0], v[3][0]));
        stf4(colB + (l + 1) * 72 + i0, make_float4(v[0][1], v[1][1], v[2][1], v[3][1]));
    }

    // ---- s5: groups g = 2w+gl; L5 lp local = 3gl, hp local = gl+1; out colA local gl*136
    if (lane < 34) {                          // 2 groups * TPG(136/8=17)
        const int gl  = (lane >= 17) ? 1 : 0;
        const int nl0 = (lane - 17 * gl) * 8;
        const float* p0 = colB + (3 * gl) * 72 + nl0 / 2;
        const float* p1 = colB + (gl + 1) * 72 + nl0 / 2;
        float ya[8], yb[8];
        reinterpret_cast<float4*>(ya)[0] = ldf4(p0);
        reinterpret_cast<float4*>(ya)[1] = ldf4(p0 + 4);
        reinterpret_cast<float4*>(yb)[0] = ldf4(p1);
        reinterpret_cast<float4*>(yb)[1] = ldf4(p1 + 4);
        float o[8];
        synth_core<0, EDGE>(ya, yb, lrev, hrev, ((s >> 4) - 4) + nl0, 2048, o);
        float* op = colA + gl * 136 + nl0;
        stf4(op,     make_float4(o[0], o[1], o[2], o[3]));
        stf4(op + 4, make_float4(o[4], o[5], o[6], o[7]));
    }

    // ---- s4: group g = w; r4 lp local = sww; out r3 colB (264 floats @ col base)
    if (lane < 33) {                          // TPG = 264/8
        const int nl0 = lane * 8;
        const float* p0 = colA + sww * 136 + nl0 / 2;
        const float* p1 = colA + (1 - sww) * 136 + nl0 / 2;
        float ya[8], yb[8];
        reinterpret_cast<float4*>(ya)[0] = ldf4(p0);
        reinterpret_cast<float4*>(ya)[1] = ldf4(p0 + 4);
        reinterpret_cast<float4*>(yb)[0] = ldf4(p1);
        reinterpret_cast<float4*>(yb)[1] = ldf4(p1 + 4);
        float o[8];
        synth_core<0, EDGE>(ya, yb, lrev, hrev, ((s >> 3) - 4) + nl0, 4096, o);
        stf4(colB + nl0,     make_float4(o[0], o[1], o[2], o[3]));
        stf4(colB + nl0 + 4, make_float4(o[4], o[5], o[6], o[7]));
    }
}

template<bool EDGE>
__device__ __forceinline__ void run_chunk(
    const float* __restrict__ xb, float* __restrict__ ob, int s,
    float* __restrict__ bufA, float* __restrict__ bufB,
    const f2* __restrict__ klh, const f2* __restrict__ lrev, const f2* __restrict__ hrev,
    const float* __restrict__ bss)
{
    const int tid = threadIdx.x;

    // Stage x window, base s-221: E[j]=x[base+2j] (bufA[0..1275]), O[j]=x[base+2j+1]
    {
        const int base = s - 221;
#pragma unroll
        for (int k = 0; k < 3; ++k) {
            const int j = tid + TPB * k;
            if (j < 1276) {
                const int g0 = base + 2 * j;
                if (EDGE) {
                    bufA[j]        = ((unsigned)g0       < (unsigned)NSEQ) ? xb[g0]     : 0.f;
                    bufA[1276 + j] = ((unsigned)(g0 + 1) < (unsigned)NSEQ) ? xb[g0 + 1] : 0.f;
                } else {
                    bufA[j]        = xb[g0];
                    bufA[1276 + j] = xb[g0 + 1];
                }
            }
        }
    }
    __syncthreads();

    // ---- block-wide analysis L1..L3 (r=8; L3 writes wave columns); tasks 159,158,156 ----
    analysis8<1276, 1272, 1, 16384, EDGE, 1272, 636>(bufA, bufB, klh, bss + 0, (s >> 1) - 109);
    __syncthreads();
    analysis8< 636,  632, 2,  8192, EDGE,  632, 316>(bufB, bufA, klh, bss + 2, (s >> 2) - 53);
    __syncthreads();
    analysis8< 316,  312, 4,  4096, EDGE, COLW, 156>(bufA, bufB, klh, bss + 6, (s >> 3) - 25);
    __syncthreads();

    // ---- barrier-free per-wave subtree: L4, L5, s5, s4 ----
    stretch_wave<EDGE>(bufA, bufB, klh, lrev, hrev, bss, s);
    __syncthreads();

    // ---- block-wide synthesis s3, s2; tasks 260, 258 ----
    synthN<COLW,  520, 4,  8192, EDGE>(bufB, bufA, lrev, hrev, (s >> 2) - 4);   // r3 cols -> r2
    __syncthreads();
    synthN< 520, 1032, 2, 16384, EDGE>(bufA, bufB, lrev, hrev, (s >> 1) - 4);   // r2 -> r1
    __syncthreads();

    // ---- final level (G=1) straight to global; r1 in bufB stride 1032; 256 x 8 outputs ----
    if (tid < 256) {
        const int i0 = tid * 8;
        float ya[12], yb[12];
        {
            const float* p0 = bufB + i0 / 2;          // channel 0 = lp (16B aligned)
            const float* p1 = p0 + 1032;              // channel 1 = hp
            reinterpret_cast<float4*>(ya)[0] = ldf4(p0);
            reinterpret_cast<float4*>(ya)[1] = ldf4(p0 + 4);
            reinterpret_cast<float4*>(ya)[2] = ldf4(p0 + 8);
            reinterpret_cast<float4*>(yb)[0] = ldf4(p1);
            reinterpret_cast<float4*>(yb)[1] = ldf4(p1 + 4);
            reinterpret_cast<float4*>(yb)[2] = ldf4(p1 + 8);
        }
        float o[8];
        synth_core<2, false>(ya, yb, lrev, hrev, 0, 1 << 30, o);
        stf4(ob + i0,     make_float4(o[0], o[1], o[2], o[3]));
        stf4(ob + i0 + 4, make_float4(o[4], o[5], o[6], o[7]));
    }
}

__global__ __launch_bounds__(TPB, 8) void wpt_fused(
    const float* __restrict__ x,
    const float* __restrict__ K1, const float* __restrict__ K2,
    const float* __restrict__ K3, const float* __restrict__ K4,
    const float* __restrict__ K5,
    const float* __restrict__ B1, const float* __restrict__ B2,
    const float* __restrict__ B3, const float* __restrict__ B4,
    const float* __restrict__ B5,
    float* __restrict__ out)
{
    __shared__ __align__(16) float bufA[2560];
    __shared__ __align__(16) float bufB[2560];
    __shared__ float bss[62];

    const int tid   = threadIdx.x;
    const int batch = blockIdx.x >> 4;
    const int cid   = blockIdx.x & 15;
    const int s     = cid * C0;

    // Filters in SGPRs: K1 = [lp | hp]; every level's rows are one of these two.
    float lp[8], hp[8];
#pragma unroll
    for (int t = 0; t < 8; ++t) {
        lp[t] = rfl(K1[t]);
        hp[t] = rfl(K1[8 + t]);
    }
    // Packed coefficient tables for pk_fma paths.
    f2 klh[8], lrev[4], hrev[4];
#pragma unroll
    for (int t = 0; t < 8; ++t) klh[t] = (f2){lp[t], hp[t]};
#pragma unroll
    for (int q = 0; q < 4; ++q) {
        lrev[q] = (f2){lp[6 - 2 * q], lp[7 - 2 * q]};
        hrev[q] = (f2){hp[6 - 2 * q], hp[7 - 2 * q]};
    }

    // Biases (pre-scaled by 10*log2(e)); 62 total, single pass with TPB=512
    {
        const float* bin[5] = {B1, B2, B3, B4, B5};
        const int boff[5] = {0, 2, 6, 14, 30};
#pragma unroll
        for (int l = 0; l < 5; ++l)
            for (int i = tid; i < (2 << l); i += TPB) bss[boff[l] + i] = SCG * bin[l][i];
    }

    const float* xb = x + batch * NSEQ;
    float* ob = out + batch * NSEQ + s;

    if (cid == 0 || cid == 15)
        run_chunk<true >(xb, ob, s, bufA, bufB, klh, lrev, hrev, bss);
    else
        run_chunk<false>(xb, ob, s, bufA, bufB, klh, lrev, hrev, bss);
}

extern "C" void kernel_launch(void* const* d_in, const int* in_sizes, int n_in,
                              void* d_out, int out_size, void* d_ws, size_t ws_size,
                              hipStream_t stream) {
    const int nbatch = in_sizes[0] / NSEQ;
    wpt_fused<<<dim3(nbatch * (NSEQ / C0)), dim3(TPB), 0, stream>>>(
        (const float*)d_in[0],
        (const float*)d_in[1], (const float*)d_in[2],
        (const float*)d_in[3], (const float*)d_in[4],
        (const float*)d_in[5],
        (const float*)d_in[6], (const float*)d_in[7],
        (const float*)d_in[8], (const float*)d_in[9],
        (const float*)d_in[10],
        (float*)d_out);
}

// Round 4
// 113.080 us; speedup vs baseline: 1.0579x; 1.0135x over previous
//
#include <hip/hip_runtime.h>

#define TPB 512

constexpr int NSEQ = 32768;
constexpr int C0   = 4096;               // output samples per block chunk (8 chunks/batch)
constexpr int COLW = 576;                // per-wave LDS column stride (floats) for the stretch
constexpr float SCG = 14.4269504089f;    // 10 * log2(e)

// Halos h_l = 2*h_{l+1}+3, h5=4 -> {221,109,53,25,11,4}
// Geometry: P5 = C0/32 + 8, P_{l-1} = 2*P_l + 8.
// C0=4096 padded level widths P: {2296,1144,568,280,136}; parity halves LE = P/2+... :
// staging 2300/parity; LE = {1148,572,284,140}; L5 out contiguous stride 136;
// synthesis Sout {264,520,1032,2056}; final 4096.
//
// Phase plan (7 barriers): stage | L1 | L2 | L3 | {L4,L5,s5,s4 per-wave} | s3 | s2 | final
// Task counts: 287 | 286 | 284 | (35,34,66,65 per wave) | 516 | 514 | 512.
// After L3 the 8 channel subtrees are independent; wave w owns L3-out channel w in
// LDS column w*COLW (colB: L3-out 568 -> L5 out 544 -> r3 520; colA: L4 out 560 -> r4 528).
// synthN phases with TOT>TPB let the first TOT-TPB threads run a second task.
//
// bufA: stage (4600) | L2-out (4576) | stretch cols (4608) | r2 (4128) -> 4608
// bufB: L1-out (4592) | L3-out cols / stretch (4608) | r1 (4112) -> 4608
// LDS = (4608+4608+62)*4 = 37112 B -> exactly 4 blocks/CU (148 KB, 32 waves).
// Grid = 128 batches * 8 chunks = 1024 blocks = 4 * 256 CUs: ONE residency generation.

typedef float f2 __attribute__((ext_vector_type(2)));

__device__ __forceinline__ f2 sp(float x) { return (f2){x, x}; }
__device__ __forceinline__ f2 fma2(f2 a, f2 b, f2 c) { return __builtin_elementwise_fma(a, b, c); }

__device__ __forceinline__ float4 ldf4(const float* p) { return *reinterpret_cast<const float4*>(p); }
__device__ __forceinline__ void   stf4(float* p, const float4 v) { *reinterpret_cast<float4*>(p) = v; }

__device__ __forceinline__ float rfl(float x) {
    return __builtin_bit_cast(float, __builtin_amdgcn_readfirstlane(__builtin_bit_cast(int, x)));
}

// Packed gate: y * (sigmoid(10(y-b)) + sigmoid(-10(y+b))) on both halves; tb = SCG*b.
__device__ __forceinline__ f2 gated2(f2 y, f2 tb) {
    f2 t1 = fma2(y, sp(-SCG), tb);
    f2 t2 = fma2(y, sp( SCG), tb);
    f2 s;
    s[0] = __builtin_amdgcn_rcpf(1.f + __builtin_amdgcn_exp2f(t1[0]))
         + __builtin_amdgcn_rcpf(1.f + __builtin_amdgcn_exp2f(t2[0]));
    s[1] = __builtin_amdgcn_rcpf(1.f + __builtin_amdgcn_exp2f(t1[1]))
         + __builtin_amdgcn_rcpf(1.f + __builtin_amdgcn_exp2f(t2[1]));
    return y * s;
}

// Block-wide analysis, r=8 per task, packed (yl,yh). klh[t] = (lp[t], hp[t]).
template<int LEin, int P, int PAIRS, int Nlev, bool EDGE, int OUTSTRIDE, int EOOFF>
__device__ __forceinline__ void analysis8(
    const float* __restrict__ in, float* __restrict__ out,
    const f2* __restrict__ klh, const float* __restrict__ bias, int outBase)
{
    constexpr int TPC = P / 8;
    constexpr int TOT = PAIRS * TPC;
    static_assert(TOT <= TPB, "analysis phase must be single-generation");
    const int task = threadIdx.x;
    if (task < TOT) {
        const int c  = task / TPC;
        const int i0 = (task - c * TPC) * 8;

        const float* pe = in + c * (2 * LEin) + i0;
        const float* po = pe + LEin;
        float a[12], b[12];
        reinterpret_cast<float4*>(a)[0] = ldf4(pe);
        reinterpret_cast<float4*>(a)[1] = ldf4(pe + 4);
        reinterpret_cast<float4*>(a)[2] = ldf4(pe + 8);
        reinterpret_cast<float4*>(b)[0] = ldf4(po);
        reinterpret_cast<float4*>(b)[1] = ldf4(po + 4);
        reinterpret_cast<float4*>(b)[2] = ldf4(po + 8);

        const int sw    = c & 1;
        const int ch_lp = 2 * c + sw;
        const int ch_hp = 2 * c + 1 - sw;
        const f2  tb    = (f2){bias[ch_lp], bias[ch_hp]};

        const int j0 = i0 >> 1;
        float* ol = out + ch_lp * OUTSTRIDE;
        float* oh = out + ch_hp * OUTSTRIDE;

#pragma unroll
        for (int par = 0; par < 2; ++par) {          // par=0 -> E plane, par=1 -> O plane
            f2 w[4];
#pragma unroll
            for (int k = 0; k < 4; ++k) {
                const int r = 2 * k + par;
                f2 y = (f2){0.f, 0.f};
#pragma unroll
                for (int u = 0; u < 4; ++u) {
                    y = fma2(sp(a[r + u]), klh[2 * u], y);
                    y = fma2(sp(b[r + u]), klh[2 * u + 1], y);
                }
                y = gated2(y, tb);
                if (EDGE) {
                    const bool ok = ((unsigned)(outBase + i0 + r) < (unsigned)Nlev);
                    y[0] = ok ? y[0] : 0.f;
                    y[1] = ok ? y[1] : 0.f;
                }
                w[k] = y;
            }
            stf4(ol + par * EOOFF + j0, make_float4(w[0][0], w[1][0], w[2][0], w[3][0]));
            stf4(oh + par * EOOFF + j0, make_float4(w[0][1], w[1][1], w[2][1], w[3][1]));
        }
    }
}

// Packed synthesis core: 8 outputs from ya/yb windows.
// o[0], o[7] scalar; pairs (o1,o2),(o3,o4),(o5,o6) packed with broadcast ya/yb.
// lrev[q] = (lp[6-2q], lp[7-2q]); hrev[q] = (hp[6-2q], hp[7-2q]).  JROFF: window offset.
template<int JROFF, bool EDGE>
__device__ __forceinline__ void synth_core(
    const float* __restrict__ ya, const float* __restrict__ yb,
    const f2* __restrict__ lrev, const f2* __restrict__ hrev,
    int gpos, int Nlev, float* __restrict__ o)
{
    f2 p1 = (f2){0.f, 0.f}, p2 = (f2){0.f, 0.f}, p3 = (f2){0.f, 0.f};
    float o0 = 0.f, o7 = 0.f;
#pragma unroll
    for (int q = 0; q < 4; ++q) {
        const f2 cl = lrev[q], ch = hrev[q];
        o0 = fmaf(ya[JROFF + q],     cl[1], o0);
        o0 = fmaf(yb[JROFF + q],     ch[1], o0);
        o7 = fmaf(ya[JROFF + 4 + q], cl[0], o7);
        o7 = fmaf(yb[JROFF + 4 + q], ch[0], o7);
        p1 = fma2(sp(ya[JROFF + 1 + q]), cl, p1);
        p1 = fma2(sp(yb[JROFF + 1 + q]), ch, p1);
        p2 = fma2(sp(ya[JROFF + 2 + q]), cl, p2);
        p2 = fma2(sp(yb[JROFF + 2 + q]), ch, p2);
        p3 = fma2(sp(ya[JROFF + 3 + q]), cl, p3);
        p3 = fma2(sp(yb[JROFF + 3 + q]), ch, p3);
    }
    o[0] = o0;    o[1] = p1[0]; o[2] = p1[1]; o[3] = p2[0];
    o[4] = p2[1]; o[5] = p3[0]; o[6] = p3[1]; o[7] = o7;
    if (EDGE) {
#pragma unroll
        for (int r = 0; r < 8; ++r) {
            const bool ok = ((unsigned)(gpos + r) < (unsigned)Nlev);
            o[r] = ok ? o[r] : 0.f;
        }
    }
}

// Block-wide synthesis r=8.  TOT may exceed TPB by a few: first TOT-TPB threads
// run a second task (compile-time unrolled, guarded).
template<int INSTRIDE, int Sout, int G, int Nlev, bool EDGE>
__device__ __forceinline__ void synthN(
    const float* __restrict__ in, float* __restrict__ out,
    const f2* __restrict__ lrev, const f2* __restrict__ hrev, int outBase)
{
    constexpr int TPG = Sout / 8;
    constexpr int TOT = G * TPG;
    static_assert(TOT <= 2 * TPB, "synth phase must fit in two generations");
#pragma unroll
    for (int t = threadIdx.x; t < TOT; t += TPB) {
        const int g   = t / TPG;
        const int nl0 = (t - g * TPG) * 8;
        const int sw  = g & 1;

        float ya[8], yb[8];
        {
            const float* p0 = in + (2 * g + sw)     * INSTRIDE + nl0 / 2;   // lp channel
            const float* p1 = in + (2 * g + 1 - sw) * INSTRIDE + nl0 / 2;   // hp channel
            reinterpret_cast<float4*>(ya)[0] = ldf4(p0);
            reinterpret_cast<float4*>(ya)[1] = ldf4(p0 + 4);
            reinterpret_cast<float4*>(yb)[0] = ldf4(p1);
            reinterpret_cast<float4*>(yb)[1] = ldf4(p1 + 4);
        }
        float o[8];
        synth_core<0, EDGE>(ya, yb, lrev, hrev, outBase + nl0, Nlev, o);
        float* op = out + g * Sout + nl0;
        stf4(op,     make_float4(o[0], o[1], o[2], o[3]));
        stf4(op + 4, make_float4(o[4], o[5], o[6], o[7]));
    }
}

// Per-wave barrier-free stretch: L4, L5, s5, s4 inside wave-column w.
template<bool EDGE>
__device__ __forceinline__ void stretch_wave(
    float* __restrict__ bufA, float* __restrict__ bufB,
    const f2* __restrict__ klh, const f2* __restrict__ lrev, const f2* __restrict__ hrev,
    const float* __restrict__ bss, int s)
{
    const int w    = threadIdx.x >> 6;       // subtree = L3-out channel
    const int lane = threadIdx.x & 63;
    float* colA = bufA + w * COLW;
    float* colB = bufB + w * COLW;
    const int sww = w & 1;

    // ---- L4 analysis (r=8): colB (E@0,O@284) -> colA local {sww,1-sww}, stride 280, EO 140
    if (lane < 35) {                          // P4/8 = 280/8
        const int i0 = lane * 8;
        const float* pe = colB + i0;
        const float* po = pe + 284;
        float a[12], b[12];
        reinterpret_cast<float4*>(a)[0] = ldf4(pe);
        reinterpret_cast<float4*>(a)[1] = ldf4(pe + 4);
        reinterpret_cast<float4*>(a)[2] = ldf4(pe + 8);
        reinterpret_cast<float4*>(b)[0] = ldf4(po);
        reinterpret_cast<float4*>(b)[1] = ldf4(po + 4);
        reinterpret_cast<float4*>(b)[2] = ldf4(po + 8);
        const f2 tb = (f2){bss[14 + 2 * w + sww], bss[14 + 2 * w + 1 - sww]};
        const int j0 = i0 >> 1;
        float* ol = colA + sww * 280;
        float* oh = colA + (1 - sww) * 280;
#pragma unroll
        for (int par = 0; par < 2; ++par) {
            f2 v[4];
#pragma unroll
            for (int k = 0; k < 4; ++k) {
                const int r = 2 * k + par;
                f2 y = (f2){0.f, 0.f};
#pragma unroll
                for (int u = 0; u < 4; ++u) {
                    y = fma2(sp(a[r + u]), klh[2 * u], y);
                    y = fma2(sp(b[r + u]), klh[2 * u + 1], y);
                }
                y = gated2(y, tb);
                if (EDGE) {
                    const bool ok = ((unsigned)(((s >> 4) - 11) + i0 + r) < 2048u);
                    y[0] = ok ? y[0] : 0.f;
                    y[1] = ok ? y[1] : 0.f;
                }
                v[k] = y;
            }
            stf4(ol + par * 140 + j0, make_float4(v[0][0], v[1][0], v[2][0], v[3][0]));
            stf4(oh + par * 140 + j0, make_float4(v[0][1], v[1][1], v[2][1], v[3][1]));
        }
    }

    // ---- L5 analysis (LAST, r=8): local l (global c=2w+l) -> colB contiguous stride 136
    // global out ch = 4w + {3l (lp), l+1 (hp)} since sw = c&1 = l.
    if (lane < 34) {                          // 2 ch * (136/8 = 17)
        const int l  = (lane >= 17) ? 1 : 0;
        const int i0 = (lane - 17 * l) * 8;
        const float* pe = colA + l * 280 + i0;
        const float* po = pe + 140;
        float a[12], b[12];
        reinterpret_cast<float4*>(a)[0] = ldf4(pe);
        reinterpret_cast<float4*>(a)[1] = ldf4(pe + 4);
        reinterpret_cast<float4*>(a)[2] = ldf4(pe + 8);
        reinterpret_cast<float4*>(b)[0] = ldf4(po);
        reinterpret_cast<float4*>(b)[1] = ldf4(po + 4);
        reinterpret_cast<float4*>(b)[2] = ldf4(po + 8);
        const int cg = 2 * w + l;
        const f2 tb = (f2){bss[30 + 2 * cg + l], bss[30 + 2 * cg + 1 - l]};
        f2 v[8];
#pragma unroll
        for (int r = 0; r < 8; ++r) {
            f2 y = (f2){0.f, 0.f};
#pragma unroll
            for (int u = 0; u < 4; ++u) {
                y = fma2(sp(a[r + u]), klh[2 * u], y);
                y = fma2(sp(b[r + u]), klh[2 * u + 1], y);
            }
            y = gated2(y, tb);
            if (EDGE) {
                const bool ok = ((unsigned)(((s >> 5) - 4) + i0 + r) < 1024u);
                y[0] = ok ? y[0] : 0.f;
                y[1] = ok ? y[1] : 0.f;
            }
            v[r] = y;
        }
        float* plo = colB + (3 * l) * 136 + i0;
        float* phi = colB + (l + 1) * 136 + i0;
        stf4(plo,     make_float4(v[0][0], v[1][0], v[2][0], v[3][0]));
        stf4(plo + 4, make_float4(v[4][0], v[5][0], v[6][0], v[7][0]));
        stf4(phi,     make_float4(v[0][1], v[1][1], v[2][1], v[3][1]));
        stf4(phi + 4, make_float4(v[4][1], v[5][1], v[6][1], v[7][1]));
    }

    // ---- s5: groups gl=0,1; L5 lp local = 3gl, hp local = gl+1; out colA local gl*264
    // 66 tasks: lanes 0,1 run a second task.
#pragma unroll
    for (int t = lane; t < 66; t += 64) {     // TPG = 264/8 = 33
        const int gl  = (t >= 33) ? 1 : 0;
        const int nl0 = (t - 33 * gl) * 8;
        const float* p0 = colB + (3 * gl) * 136 + nl0 / 2;
        const float* p1 = colB + (gl + 1) * 136 + nl0 / 2;
        float ya[8], yb[8];
        reinterpret_cast<float4*>(ya)[0] = ldf4(p0);
        reinterpret_cast<float4*>(ya)[1] = ldf4(p0 + 4);
        reinterpret_cast<float4*>(yb)[0] = ldf4(p1);
        reinterpret_cast<float4*>(yb)[1] = ldf4(p1 + 4);
        float o[8];
        synth_core<0, EDGE>(ya, yb, lrev, hrev, ((s >> 4) - 4) + nl0, 2048, o);
        float* op = colA + gl * 264 + nl0;
        stf4(op,     make_float4(o[0], o[1], o[2], o[3]));
        stf4(op + 4, make_float4(o[4], o[5], o[6], o[7]));
    }

    // ---- s4: group g = w; r4 lp local = sww; out r3 colB (520 floats @ col base)
    // 65 tasks: lane 0 runs a second task.
#pragma unroll
    for (int t = lane; t < 65; t += 64) {     // TPG = 520/8
        const int nl0 = t * 8;
        const float* p0 = colA + sww * 264 + nl0 / 2;
        const float* p1 = colA + (1 - sww) * 264 + nl0 / 2;
        float ya[8], yb[8];
        reinterpret_cast<float4*>(ya)[0] = ldf4(p0);
        reinterpret_cast<float4*>(ya)[1] = ldf4(p0 + 4);
        reinterpret_cast<float4*>(yb)[0] = ldf4(p1);
        reinterpret_cast<float4*>(yb)[1] = ldf4(p1 + 4);
        float o[8];
        synth_core<0, EDGE>(ya, yb, lrev, hrev, ((s >> 3) - 4) + nl0, 4096, o);
        stf4(colB + nl0,     make_float4(o[0], o[1], o[2], o[3]));
        stf4(colB + nl0 + 4, make_float4(o[4], o[5], o[6], o[7]));
    }
}

template<bool EDGE>
__device__ __forceinline__ void run_chunk(
    const float* __restrict__ xb, float* __restrict__ ob, int s,
    float* __restrict__ bufA, float* __restrict__ bufB,
    const f2* __restrict__ klh, const f2* __restrict__ lrev, const f2* __restrict__ hrev,
    const float* __restrict__ bss)
{
    const int tid = threadIdx.x;

    // Stage x window, base s-221: E[j]=x[base+2j] (bufA[0..2299]), O[j]=x[base+2j+1]
    {
        const int base = s - 221;
#pragma unroll
        for (int k = 0; k < 5; ++k) {
            const int j = tid + TPB * k;
            if (j < 2300) {
                const int g0 = base + 2 * j;
                if (EDGE) {
                    bufA[j]        = ((unsigned)g0       < (unsigned)NSEQ) ? xb[g0]     : 0.f;
                    bufA[2300 + j] = ((unsigned)(g0 + 1) < (unsigned)NSEQ) ? xb[g0 + 1] : 0.f;
                } else {
                    bufA[j]        = xb[g0];
                    bufA[2300 + j] = xb[g0 + 1];
                }
            }
        }
    }
    __syncthreads();

    // ---- block-wide analysis L1..L3 (r=8; L3 writes wave columns); tasks 287,286,284 ----
    analysis8<2300, 2296, 1, 16384, EDGE, 2296, 1148>(bufA, bufB, klh, bss + 0, (s >> 1) - 109);
    __syncthreads();
    analysis8<1148, 1144, 2,  8192, EDGE, 1144,  572>(bufB, bufA, klh, bss + 2, (s >> 2) - 53);
    __syncthreads();
    analysis8< 572,  568, 4,  4096, EDGE, COLW,  284>(bufA, bufB, klh, bss + 6, (s >> 3) - 25);
    __syncthreads();

    // ---- barrier-free per-wave subtree: L4, L5, s5, s4 ----
    stretch_wave<EDGE>(bufA, bufB, klh, lrev, hrev, bss, s);
    __syncthreads();

    // ---- block-wide synthesis s3, s2; tasks 516, 514 ----
    synthN<COLW, 1032, 4,  8192, EDGE>(bufB, bufA, lrev, hrev, (s >> 2) - 4);   // r3 cols -> r2
    __syncthreads();
    synthN<1032, 2056, 2, 16384, EDGE>(bufA, bufB, lrev, hrev, (s >> 1) - 4);   // r2 -> r1
    __syncthreads();

    // ---- final level (G=1) straight to global; r1 in bufB stride 2056; 512 x 8 outputs ----
    {
        const int i0 = tid * 8;
        float ya[12], yb[12];
        {
            const float* p0 = bufB + i0 / 2;          // channel 0 = lp (16B aligned)
            const float* p1 = p0 + 2056;              // channel 1 = hp
            reinterpret_cast<float4*>(ya)[0] = ldf4(p0);
            reinterpret_cast<float4*>(ya)[1] = ldf4(p0 + 4);
            reinterpret_cast<float4*>(ya)[2] = ldf4(p0 + 8);
            reinterpret_cast<float4*>(yb)[0] = ldf4(p1);
            reinterpret_cast<float4*>(yb)[1] = ldf4(p1 + 4);
            reinterpret_cast<float4*>(yb)[2] = ldf4(p1 + 8);
        }
        float o[8];
        synth_core<2, false>(ya, yb, lrev, hrev, 0, 1 << 30, o);
        stf4(ob + i0,     make_float4(o[0], o[1], o[2], o[3]));
        stf4(ob + i0 + 4, make_float4(o[4], o[5], o[6], o[7]));
    }
}

__global__ __launch_bounds__(TPB, 8) void wpt_fused(
    const float* __restrict__ x,
    const float* __restrict__ K1, const float* __restrict__ K2,
    const float* __restrict__ K3, const float* __restrict__ K4,
    const float* __restrict__ K5,
    const float* __restrict__ B1, const float* __restrict__ B2,
    const float* __restrict__ B3, const float* __restrict__ B4,
    const float* __restrict__ B5,
    float* __restrict__ out)
{
    __shared__ __align__(16) float bufA[4608];
    __shared__ __align__(16) float bufB[4608];
    __shared__ float bss[62];

    const int tid   = threadIdx.x;
    const int batch = blockIdx.x >> 3;
    const int cid   = blockIdx.x & 7;
    const int s     = cid * C0;

    // Filters in SGPRs: K1 = [lp | hp]; every level's rows are one of these two.
    float lp[8], hp[8];
#pragma unroll
    for (int t = 0; t < 8; ++t) {
        lp[t] = rfl(K1[t]);
        hp[t] = rfl(K1[8 + t]);
    }
    // Packed coefficient tables for pk_fma paths.
    f2 klh[8], lrev[4], hrev[4];
#pragma unroll
    for (int t = 0; t < 8; ++t) klh[t] = (f2){lp[t], hp[t]};
#pragma unroll
    for (int q = 0; q < 4; ++q) {
        lrev[q] = (f2){lp[6 - 2 * q], lp[7 - 2 * q]};
        hrev[q] = (f2){hp[6 - 2 * q], hp[7 - 2 * q]};
    }

    // Biases (pre-scaled by 10*log2(e)); 62 total, single pass with TPB=512
    {
        const float* bin[5] = {B1, B2, B3, B4, B5};
        const int boff[5] = {0, 2, 6, 14, 30};
#pragma unroll
        for (int l = 0; l < 5; ++l)
            for (int i = tid; i < (2 << l); i += TPB) bss[boff[l] + i] = SCG * bin[l][i];
    }

    const float* xb = x + batch * NSEQ;
    float* ob = out + batch * NSEQ + s;

    if (cid == 0 || cid == 7)
        run_chunk<true >(xb, ob, s, bufA, bufB, klh, lrev, hrev, bss);
    else
        run_chunk<false>(xb, ob, s, bufA, bufB, klh, lrev, hrev, bss);
}

extern "C" void kernel_launch(void* const* d_in, const int* in_sizes, int n_in,
                              void* d_out, int out_size, void* d_ws, size_t ws_size,
                              hipStream_t stream) {
    const int nbatch = in_sizes[0] / NSEQ;
    wpt_fused<<<dim3(nbatch * (NSEQ / C0)), dim3(TPB), 0, stream>>>(
        (const float*)d_in[0],
        (const float*)d_in[1], (const float*)d_in[2],
        (const float*)d_in[3], (const float*)d_in[4],
        (const float*)d_in[5],
        (const float*)d_in[6], (const float*)d_in[7],
        (const float*)d_in[8], (const float*)d_in[9],
        (const float*)d_in[10],
        (float*)d_out);
}